// Round 3
// baseline (286.665 us; speedup 1.0000x reference)
//
#include <hip/hip_runtime.h>
#include <hip/hip_cooperative_groups.h>
#include <stdint.h>
#include <math.h>

namespace cg = cooperative_groups;

// Problem constants (match reference setup_inputs)
#define IMGF   512.0f
#define A_N    49104
#define B_N    8
#define C_N    80
#define K_N    256
#define IOU_T  0.5f
#define NBIN   4096      // linear bins: bin = (int)(score * 4096), clamped
#define CAP    2048      // per-batch candidate capacity (nc expected ~310)
#define TOTAL_A (B_N * A_N)   // 392832

__device__ __forceinline__ int bin_of(uint32_t key) {
    float s = __uint_as_float(key);          // s in [0,1)
    int b = (int)(s * 4096.0f);
    return b > 4095 ? 4095 : b;
}

// sequential argmax over a float4 (ascending class visit order == jnp.argmax
// first-max semantics)
__device__ __forceinline__ void amax4(float4 v, int cbase, float& best, int& cls) {
    if (v.x > best) { best = v.x; cls = cbase + 0; }
    if (v.y > best) { best = v.y; cls = cbase + 1; }
    if (v.z > best) { best = v.z; cls = cbase + 2; }
    if (v.w > best) { best = v.w; cls = cbase + 3; }
}

// ---------------------------------------------------------------------------
// ONE cooperative kernel, GRID blocks x 1024 threads (GRID=512 -> 2 blocks/CU,
// 32 waves/CU; launch_bounds(1024,8) caps VGPR<=64 so 2-block residency holds).
//   Phase A: score+argmax, 4 lanes/anchor, tiles of 256 anchors/block,
//     2-deep software pipeline (10 float4 in flight) -> HBM-bound, not
//     latency-bound (R2 measured the unpipelined 16-wave version at ~60us,
//     cache-state-insensitive => latency-bound; this fixes both causes).
//     Stores keys (sigmoid bits) + labels (u8 argmax) -- labels make select's
//     phase-5 logit gather unnecessary.
//   grid.sync()
//   Phase B (blocks 0..7, one per batch): histogram -> threshold bin ->
//     compact -> counting-rank sort -> decode -> NMS bitmask -> outputs.
//     Phase 6b batched 4 rows/group (hoisted LDS loads, ~3x fewer
//     latency-chain stalls than row-at-a-time).
// ---------------------------------------------------------------------------
template <int GRID>
__global__ __launch_bounds__(1024, 8) void fused_kernel(
    const float* __restrict__ logits,
    const float* __restrict__ regs,
    const float* __restrict__ anchors,
    uint32_t* __restrict__ keys,
    uint8_t* __restrict__ labels,
    float* __restrict__ out)
{
    const int tid  = threadIdx.x;            // 0..1023
    const int lane = tid & 63, wv = tid >> 6;
    const int grp  = lane >> 2, j = lane & 3;
    const int STR  = GRID * 256;

    // ---- Phase A: score + argmax, 2-deep pipelined tiles ----
    {
        float4 A0, A1, A2, A3, A4, B0, B1, B2, B3, B4;
#define LOAD5(R, g) { const float4* p = (const float4*)(logits + (size_t)(g) * C_N); \
        R##0 = p[j]; R##1 = p[j + 4]; R##2 = p[j + 8]; R##3 = p[j + 12]; R##4 = p[j + 16]; }
#define RED_STORE(R, g) { \
        float best = -INFINITY; int cls = 0; \
        amax4(R##0,      4 * j, best, cls); \
        amax4(R##1, 16 + 4 * j, best, cls); \
        amax4(R##2, 32 + 4 * j, best, cls); \
        amax4(R##3, 48 + 4 * j, best, cls); \
        amax4(R##4, 64 + 4 * j, best, cls); \
        { float mo = __shfl_xor(best, 1, 64); int co = __shfl_xor(cls, 1, 64); \
          if (mo > best || (mo == best && co < cls)) { best = mo; cls = co; } } \
        { float mo = __shfl_xor(best, 2, 64); int co = __shfl_xor(cls, 2, 64); \
          if (mo > best || (mo == best && co < cls)) { best = mo; cls = co; } } \
        if (j == 0) { \
            float s = 1.0f / (1.0f + expf(-best)); \
            if (!(s > 0.01f)) s = 0.0f; \
            keys[g] = __float_as_uint(s); \
            labels[g] = (uint8_t)cls; \
        } }

        int g = blockIdx.x * 256 + wv * 16 + grp;   // < GRID*256 <= TOTAL_A
        LOAD5(A, g);
        while (true) {
            int gn = g + STR;
            bool has = gn < TOTAL_A;                // wave-uniform (boundary % 16 == 0)
            if (has) { LOAD5(B, gn); }
            RED_STORE(A, g);
            if (!has) break;
            g = gn;
            int gm = g + STR;
            bool has2 = gm < TOTAL_A;
            if (has2) { LOAD5(A, gm); }
            RED_STORE(B, g);
            if (!has2) break;
            g = gm;
        }
#undef LOAD5
#undef RED_STORE
    }

    cg::this_grid().sync();

    // ---- Phase B: per-batch select+NMS on blocks 0..7 ----
    if (blockIdx.x >= B_N) return;
    const int b = blockIdx.x;

    __shared__ uint32_t hist[NBIN];                 // 16 KB
    __shared__ int wtots[16];
    __shared__ int sh_T, sh_nc;
    __shared__ unsigned long long cand[CAP];        // 16 KB
    __shared__ unsigned long long sorted[K_N];      // 2 KB
    __shared__ float4 sbox[K_N];
    __shared__ float  sscore[K_N];
    __shared__ int    slab[K_N];
    __shared__ unsigned long long supr[K_N][4];     // 8 KB
    __shared__ unsigned long long keepw[4];

    const uint32_t* kb = keys + (size_t)b * A_N;
    const uint4* kb4 = (const uint4*)kb;            // A_N % 4 == 0, 16B aligned
    const int N4 = A_N / 4;                         // 12276

    // ---- Phase 1: histogram (linear bins) ----
    for (int i = tid; i < NBIN; i += 1024) hist[i] = 0;
    if (tid == 0) sh_nc = 0;
    __syncthreads();
    for (int i = tid; i < N4; i += 1024) {
        uint4 v = kb4[i];
        atomicAdd(&hist[bin_of(v.x)], 1u);
        atomicAdd(&hist[bin_of(v.y)], 1u);
        atomicAdd(&hist[bin_of(v.z)], 1u);
        atomicAdd(&hist[bin_of(v.w)], 1u);
    }
    __syncthreads();

    // ---- Phase 2: threshold bin via wave-shuffle suffix scan (2 barriers) ----
    const int lo = tid * 4;                         // 4 bins per thread
    int seg = (int)hist[lo] + (int)hist[lo + 1]
            + (int)hist[lo + 2] + (int)hist[lo + 3];
    int s1 = seg;                                   // within-wave inclusive suffix
#pragma unroll
    for (int off = 1; off < 64; off <<= 1) {
        int v = __shfl_down(s1, off, 64);
        if (lane + off < 64) s1 += v;
    }
    if (lane == 0) wtots[wv] = s1;                  // wave total
    __syncthreads();
    int wsuf = 0;
    for (int w = wv + 1; w < 16; ++w) wsuf += wtots[w];
    int above = wsuf + (s1 - seg);                  // keys in strictly-later segs
    if (above < K_N && above + seg >= K_N) {        // exactly one thread true
        int cum = above;
        for (int bin = lo + 3; bin >= lo; --bin) {
            int c = (int)hist[bin];
            if (cum + c >= K_N) { sh_T = bin; break; }
            cum += c;
        }
    }
    __syncthreads();
    const int T = sh_T;

    // ---- Phase 3: compact candidates (bin >= T) ----
    for (int i = tid; i < N4; i += 1024) {
        uint4 v = kb4[i];
        uint32_t ks[4] = { v.x, v.y, v.z, v.w };
#pragma unroll
        for (int q = 0; q < 4; ++q) {
            if (bin_of(ks[q]) >= T) {
                int p = atomicAdd(&sh_nc, 1);
                if (p < CAP)
                    cand[p] = ((unsigned long long)ks[q] << 32)
                            | (unsigned long long)(0xFFFFFFFFu - (uint32_t)(4 * i + q));
            }
        }
    }
    if (tid < K_N) sorted[tid] = 0ull;
    __syncthreads();
    int nc = sh_nc; if (nc > CAP) nc = CAP;

    // ---- Phase 4: counting-rank sort (broadcast reads, no barriers) ----
    for (int i = tid; i < nc; i += 1024) {
        unsigned long long me = cand[i];
        int r = 0;
        for (int jq = 0; jq < nc; ++jq) r += (cand[jq] > me);
        if (r < K_N) sorted[r] = me;
    }
    __syncthreads();

    // ---- Phase 5: decode top-256 + label lookup (threads 0..255) ----
    if (tid < K_N) {
#pragma clang fp contract(off)
        unsigned long long cv = sorted[tid];
        uint32_t key = (uint32_t)(cv >> 32);
        uint32_t ai  = 0xFFFFFFFFu - (uint32_t)cv;
        if (ai >= (uint32_t)A_N) ai = 0;   // pad entries (score 0, unkept)
        int a = (int)ai;
        float s = __uint_as_float(key);
        sscore[tid] = s;
        slab[tid] = (int)labels[(size_t)b * A_N + a];   // precomputed in score

        float ax0 = anchors[4 * a + 0], ay0 = anchors[4 * a + 1];
        float ax1 = anchors[4 * a + 2], ay1 = anchors[4 * a + 3];
        float aw = ax1 - ax0, ah = ay1 - ay0;
        float acx = ax0 + 0.5f * aw, acy = ay0 + 0.5f * ah;
        const float* r = regs + ((size_t)b * A_N + a) * 4;
        float dx = r[0], dy = r[1], dw = r[2], dh = r[3];
        float cx = acx + dx * aw;
        float cy = acy + dy * ah;
        dw = fminf(fmaxf(dw, -4.0f), 4.0f);
        dh = fminf(fmaxf(dh, -4.0f), 4.0f);
        float w = aw * expf(dw);
        float h = ah * expf(dh);
        float x0 = cx - 0.5f * w, y0 = cy - 0.5f * h;
        float x1 = cx + 0.5f * w, y1 = cy + 0.5f * h;
        x0 = fminf(fmaxf(x0, 0.0f), IMGF);
        y0 = fminf(fmaxf(y0, 0.0f), IMGF);
        x1 = fminf(fmaxf(x1, 0.0f), IMGF);
        y1 = fminf(fmaxf(y1, 0.0f), IMGF);
        sbox[tid] = make_float4(x0, y0, x1, y1);
    }
    __syncthreads();

    // ---- Phase 6a: suppression matrix, one u64 word per thread ----
    {
#pragma clang fp contract(off)
        const int row = tid & 255, gq = tid >> 8;   // word gq of row
        float4 bi = sbox[row];
        float areai = fmaxf(bi.z - bi.x, 0.0f) * fmaxf(bi.w - bi.y, 0.0f);
        unsigned long long m = 0;
        const int jlo = gq * 64, jhi = jlo + 64;
        int start = row + 1 > jlo ? row + 1 : jlo;
        for (int jx = start; jx < jhi; ++jx) {
            float4 bj = sbox[jx];
            float areaj = fmaxf(bj.z - bj.x, 0.0f) * fmaxf(bj.w - bj.y, 0.0f);
            float lx = fmaxf(bi.x, bj.x), ly = fmaxf(bi.y, bj.y);
            float rx = fminf(bi.z, bj.z), ry = fminf(bi.w, bj.w);
            float iw = fmaxf(rx - lx, 0.0f), ih = fmaxf(ry - ly, 0.0f);
            float inter = iw * ih;
            float uni = areai + areaj - inter;
            float iou = inter / fmaxf(uni, 1e-8f);
            if (iou > IOU_T) m |= 1ull << (jx & 63);
        }
        supr[row][gq] = m;
    }
    // keep0 = score > 0 (threads 0..255 = waves 0..3)
    if (tid < K_N) {
        unsigned long long ball = __ballot(sscore[tid] > 0.0f);
        if ((tid & 63) == 0) keepw[tid >> 6] = ball;
    }
    __syncthreads();

    // ---- Phase 6b: serial greedy scan, 4 rows/group with hoisted loads.
    //      kc is read LIVE per row (token-pasted k##c), so within-group
    //      suppression ordering matches the reference exactly. ----
    if (tid == 0) {
        unsigned long long k0 = keepw[0], k1 = keepw[1], k2 = keepw[2], k3 = keepw[3];
#define NMS_CHUNK(c, kc)                                                       \
        for (int l = 0; l < 64; l += 4) {                                      \
            const int i = (c) * 64 + l;                                        \
            unsigned long long wA0 = supr[i+0][0], wA1 = supr[i+0][1],         \
                               wA2 = supr[i+0][2], wA3 = supr[i+0][3];         \
            unsigned long long wB0 = supr[i+1][0], wB1 = supr[i+1][1],         \
                               wB2 = supr[i+1][2], wB3 = supr[i+1][3];         \
            unsigned long long wC0 = supr[i+2][0], wC1 = supr[i+2][1],         \
                               wC2 = supr[i+2][2], wC3 = supr[i+2][3];         \
            unsigned long long wD0 = supr[i+3][0], wD1 = supr[i+3][1],         \
                               wD2 = supr[i+3][2], wD3 = supr[i+3][3];         \
            if ((kc >> (l + 0)) & 1ull) { k0 &= ~wA0; k1 &= ~wA1; k2 &= ~wA2; k3 &= ~wA3; } \
            if ((kc >> (l + 1)) & 1ull) { k0 &= ~wB0; k1 &= ~wB1; k2 &= ~wB2; k3 &= ~wB3; } \
            if ((kc >> (l + 2)) & 1ull) { k0 &= ~wC0; k1 &= ~wC1; k2 &= ~wC2; k3 &= ~wC3; } \
            if ((kc >> (l + 3)) & 1ull) { k0 &= ~wD0; k1 &= ~wD1; k2 &= ~wD2; k3 &= ~wD3; } \
        }
        NMS_CHUNK(0, k0)
        NMS_CHUNK(1, k1)
        NMS_CHUNK(2, k2)
        NMS_CHUNK(3, k3)
#undef NMS_CHUNK
        keepw[0] = k0; keepw[1] = k1; keepw[2] = k2; keepw[3] = k3;
    }
    __syncthreads();

    // ---- Phase 7: outputs: dets [B,K,5] ++ labels [B,K] ++ keep [B,K] ----
    if (tid < K_N) {
        float keepf = ((keepw[tid >> 6] >> (tid & 63)) & 1ull) ? 1.0f : 0.0f;
        float4 bx = sbox[tid];
        float s = sscore[tid];
        float* det = out + ((size_t)b * K_N + tid) * 5;
        det[0] = bx.x * keepf;
        det[1] = bx.y * keepf;
        det[2] = bx.z * keepf;
        det[3] = bx.w * keepf;
        det[4] = s * keepf;
        out[(size_t)B_N * K_N * 5 + (size_t)b * K_N + tid] = (float)slab[tid];
        out[(size_t)B_N * K_N * 5 + (size_t)B_N * K_N + (size_t)b * K_N + tid] = keepf;
    }
}

extern "C" void kernel_launch(void* const* d_in, const int* in_sizes, int n_in,
                              void* d_out, int out_size, void* d_ws, size_t ws_size,
                              hipStream_t stream)
{
    const float* logits  = (const float*)d_in[0];   // [B,A,C] fp32
    const float* regs    = (const float*)d_in[1];   // [B,A,4] fp32
    const float* anchors = (const float*)d_in[2];   // [A,4]   fp32
    float* out = (float*)d_out;

    uint32_t* keys   = (uint32_t*)d_ws;                           // B*A u32
    uint8_t*  labels = (uint8_t*)(keys + (size_t)B_N * A_N);      // B*A u8

    void* args[] = { (void*)&logits, (void*)&regs, (void*)&anchors,
                     (void*)&keys, (void*)&labels, (void*)&out };

    // prefer 512 blocks (2/CU, 32 waves/CU); fall back to 256 if residency
    // isn't granted (host-side query, runs once at capture, deterministic)
    static int grid_choice = -1;
    if (grid_choice < 0) {
        int nb = 0;
        hipError_t e = hipOccupancyMaxActiveBlocksPerMultiprocessor(
            &nb, fused_kernel<512>, 1024, 0);
        grid_choice = (e == hipSuccess && nb >= 2) ? 512 : 256;
    }
    if (grid_choice == 512) {
        hipLaunchCooperativeKernel(fused_kernel<512>, dim3(512), dim3(1024),
                                   args, 0, stream);
    } else {
        hipLaunchCooperativeKernel(fused_kernel<256>, dim3(256), dim3(1024),
                                   args, 0, stream);
    }
}

// Round 4
// 227.628 us; speedup vs baseline: 1.2594x; 1.2594x over previous
//
#include <hip/hip_runtime.h>
#include <stdint.h>
#include <math.h>

// Problem constants (match reference setup_inputs)
#define IMGF   512.0f
#define A_N    49104
#define B_N    8
#define C_N    80
#define K_N    256
#define IOU_T  0.5f
#define NBIN   4096      // linear bins: bin = (int)(score * 4096), clamped
#define CAP    2048      // per-batch candidate capacity (nc expected ~310)

__device__ __forceinline__ int bin_of(uint32_t key) {
    float s = __uint_as_float(key);          // s in [0,1)
    int b = (int)(s * 4096.0f);
    return b > 4095 ? 4095 : b;
}

// sequential argmax over a float4, ascending class order == jnp.argmax
// first-max semantics (strict > keeps the earlier class on ties)
__device__ __forceinline__ void amax4(float4 v, int cbase, float& best, int& cls) {
    if (v.x > best) { best = v.x; cls = cbase + 0; }
    if (v.y > best) { best = v.y; cls = cbase + 1; }
    if (v.z > best) { best = v.z; cls = cbase + 2; }
    if (v.w > best) { best = v.w; cls = cbase + 3; }
}

// ---------------------------------------------------------------------------
// Kernel A (R0 champion structure + fused argmax): 4 lanes per anchor,
// 5 float4 loads each (fully-consumed 64B lines per 4-lane group). Block
// streaming (6138 blocks) provides the memory pipelining — proven ~20us.
// ~17x memory-bound, so the extra ~45 VALU ops for argmax tracking are free.
// Lane j visits classes {4j..4j+3, 16+4j.., 32+.., 48+.., 64+..} in ascending
// order; cross-lane merge breaks ties by min class index => exact first-max.
// ---------------------------------------------------------------------------
__global__ __launch_bounds__(256) void score_kernel(
    const float* __restrict__ logits,
    uint32_t* __restrict__ keys,
    uint8_t* __restrict__ labels)
{
    const int tid  = threadIdx.x;
    const int lane = tid & 63;
    const int grp  = lane >> 2, j = lane & 3;
    const int g = blockIdx.x * 64 + (tid >> 6) * 16 + grp;   // anchor (flat B*A)

    const float4* p = (const float4*)(logits + (size_t)g * C_N);
    float4 v0 = p[j], v1 = p[j + 4], v2 = p[j + 8], v3 = p[j + 12], v4 = p[j + 16];
    float best = -INFINITY; int cls = 0;
    amax4(v0,      4 * j, best, cls);
    amax4(v1, 16 + 4 * j, best, cls);
    amax4(v2, 32 + 4 * j, best, cls);
    amax4(v3, 48 + 4 * j, best, cls);
    amax4(v4, 64 + 4 * j, best, cls);
    { float mo = __shfl_xor(best, 1, 64); int co = __shfl_xor(cls, 1, 64);
      if (mo > best || (mo == best && co < cls)) { best = mo; cls = co; } }
    { float mo = __shfl_xor(best, 2, 64); int co = __shfl_xor(cls, 2, 64);
      if (mo > best || (mo == best && co < cls)) { best = mo; cls = co; } }
    if (j == 0) {
        float s = 1.0f / (1.0f + expf(-best));
        if (!(s > 0.01f)) s = 0.0f;          // reference: where(s > thr, s, 0)
        keys[g] = __float_as_uint(s);        // s >= 0 -> order-preserving bits
        labels[g] = (uint8_t)cls;
    }
}

// ---------------------------------------------------------------------------
// Kernel B: one block (1024 threads) per batch. Latency-chain fixes vs R0:
//   - keys loaded ONCE into registers (12 x uint4/thread, independent loads
//     in flight), reused for phase 3 -> no 196KB re-read
//   - phase 4 rank sort reads cand[] as ulonglong2, 8 candidates/iter
//     (was 310 sequential 120-cy ds_read_b64 on 5 waves ~= 18us)
//   - phase 5 label from precomputed u8 array (no 20-float4 gather);
//     anchors/regs as float4
//   - phase 6b batched 4 rows/group with hoisted LDS loads (live-kc
//     semantics preserved == reference suppression order)
// ---------------------------------------------------------------------------
__global__ __launch_bounds__(1024) void select_nms_kernel(
    const uint32_t* __restrict__ keys,
    const uint8_t* __restrict__ labels,
    const float* __restrict__ regs,
    const float* __restrict__ anchors,
    float* __restrict__ out)
{
    const int b   = blockIdx.x;
    const int tid = threadIdx.x;          // 0..1023
    const int lane = tid & 63, wv = tid >> 6;

    __shared__ uint32_t hist[NBIN];                          // 16 KB
    __shared__ int wtots[16];
    __shared__ int sh_T, sh_nc;
    __shared__ __align__(16) unsigned long long cand[CAP];   // 16 KB
    __shared__ unsigned long long sorted[K_N];               // 2 KB
    __shared__ float4 sbox[K_N];
    __shared__ float  sscore[K_N];
    __shared__ int    slab[K_N];
    __shared__ unsigned long long supr[K_N][4];              // 8 KB
    __shared__ unsigned long long keepw[4];

    const uint32_t* kb = keys + (size_t)b * A_N;
    const uint4* kb4 = (const uint4*)kb;            // A_N % 4 == 0, 16B aligned
    const int N4 = A_N / 4;                         // 12276 = 11*1024 + 1012

    // ---- Phase 0: load all keys for this thread into registers ----
    uint4 kv[12];
#pragma unroll
    for (int t = 0; t < 11; ++t) kv[t] = kb4[tid + t * 1024];
    const bool has12 = (tid + 11 * 1024) < N4;      // tid < 1012
    if (has12) kv[11] = kb4[tid + 11 * 1024];

    // ---- Phase 1: histogram (linear bins) ----
    for (int i = tid; i < NBIN; i += 1024) hist[i] = 0;
    if (tid == 0) sh_nc = 0;
    __syncthreads();
#pragma unroll
    for (int t = 0; t < 12; ++t) {
        if (t < 11 || has12) {
            uint4 v = kv[t];
            atomicAdd(&hist[bin_of(v.x)], 1u);
            atomicAdd(&hist[bin_of(v.y)], 1u);
            atomicAdd(&hist[bin_of(v.z)], 1u);
            atomicAdd(&hist[bin_of(v.w)], 1u);
        }
    }
    __syncthreads();

    // ---- Phase 2: threshold bin via wave-shuffle suffix scan (2 barriers) ----
    const int lo = tid * 4;                         // 4 bins per thread
    int seg = (int)hist[lo] + (int)hist[lo + 1]
            + (int)hist[lo + 2] + (int)hist[lo + 3];
    int s1 = seg;                                   // within-wave inclusive suffix
#pragma unroll
    for (int off = 1; off < 64; off <<= 1) {
        int v = __shfl_down(s1, off, 64);
        if (lane + off < 64) s1 += v;
    }
    if (lane == 0) wtots[wv] = s1;                  // wave total
    __syncthreads();
    int wsuf = 0;
    for (int w = wv + 1; w < 16; ++w) wsuf += wtots[w];
    int above = wsuf + (s1 - seg);                  // keys in strictly-later segs
    if (above < K_N && above + seg >= K_N) {        // exactly one thread true
        int cum = above;
        for (int bin = lo + 3; bin >= lo; --bin) {
            int c = (int)hist[bin];
            if (cum + c >= K_N) { sh_T = bin; break; }
            cum += c;
        }
    }
    __syncthreads();
    const int T = sh_T;

    // ---- Phase 3: compact candidates (bin >= T) from registers ----
#pragma unroll
    for (int t = 0; t < 12; ++t) {
        if (t < 11 || has12) {
            uint4 v = kv[t];
            const int i = tid + t * 1024;
            uint32_t ks[4] = { v.x, v.y, v.z, v.w };
#pragma unroll
            for (int q = 0; q < 4; ++q) {
                if (bin_of(ks[q]) >= T) {
                    int p = atomicAdd(&sh_nc, 1);
                    if (p < CAP)
                        cand[p] = ((unsigned long long)ks[q] << 32)
                                | (unsigned long long)(0xFFFFFFFFu - (uint32_t)(4 * i + q));
                }
            }
        }
    }
    if (tid < K_N) sorted[tid] = 0ull;
    __syncthreads();
    int nc = sh_nc; if (nc > CAP) nc = CAP;
    // zero-pad cand up to a multiple of 8 (pads are 0 and never out-rank a
    // real entry: every real entry is > 0). If nc == CAP, no padding needed.
    const int nc8 = (nc + 7) & ~7;
    for (int i = nc + tid; i < nc8; i += 1024) cand[i] = 0ull;
    __syncthreads();

    // ---- Phase 4: counting-rank sort, vectorized 8-wide (ds_read_b128 x4
    //      independent per iter -> pipelined, was the latency chain) ----
    for (int i = tid; i < nc; i += 1024) {
        unsigned long long me = cand[i];
        int r = 0;
        for (int jq = 0; jq < nc8; jq += 8) {
            ulonglong2 c0 = *(const ulonglong2*)&cand[jq];
            ulonglong2 c1 = *(const ulonglong2*)&cand[jq + 2];
            ulonglong2 c2 = *(const ulonglong2*)&cand[jq + 4];
            ulonglong2 c3 = *(const ulonglong2*)&cand[jq + 6];
            r += (int)(c0.x > me) + (int)(c0.y > me)
               + (int)(c1.x > me) + (int)(c1.y > me)
               + (int)(c2.x > me) + (int)(c2.y > me)
               + (int)(c3.x > me) + (int)(c3.y > me);
        }
        if (r < K_N) sorted[r] = me;
    }
    __syncthreads();

    // ---- Phase 5: decode top-256 + label lookup (threads 0..255) ----
    if (tid < K_N) {
#pragma clang fp contract(off)
        unsigned long long cv = sorted[tid];
        uint32_t key = (uint32_t)(cv >> 32);
        uint32_t ai  = 0xFFFFFFFFu - (uint32_t)cv;
        if (ai >= (uint32_t)A_N) ai = 0;   // pad entries (score 0, unkept)
        int a = (int)ai;
        float s = __uint_as_float(key);
        sscore[tid] = s;
        slab[tid] = (int)labels[(size_t)b * A_N + a];   // fused in score kernel

        float4 av = ((const float4*)anchors)[a];
        float ax0 = av.x, ay0 = av.y, ax1 = av.z, ay1 = av.w;
        float aw = ax1 - ax0, ah = ay1 - ay0;
        float acx = ax0 + 0.5f * aw, acy = ay0 + 0.5f * ah;
        float4 rv = ((const float4*)regs)[(size_t)b * A_N + a];
        float dx = rv.x, dy = rv.y, dw = rv.z, dh = rv.w;
        float cx = acx + dx * aw;
        float cy = acy + dy * ah;
        dw = fminf(fmaxf(dw, -4.0f), 4.0f);
        dh = fminf(fmaxf(dh, -4.0f), 4.0f);
        float w = aw * expf(dw);
        float h = ah * expf(dh);
        float x0 = cx - 0.5f * w, y0 = cy - 0.5f * h;
        float x1 = cx + 0.5f * w, y1 = cy + 0.5f * h;
        x0 = fminf(fmaxf(x0, 0.0f), IMGF);
        y0 = fminf(fmaxf(y0, 0.0f), IMGF);
        x1 = fminf(fmaxf(x1, 0.0f), IMGF);
        y1 = fminf(fmaxf(y1, 0.0f), IMGF);
        sbox[tid] = make_float4(x0, y0, x1, y1);
    }
    __syncthreads();

    // ---- Phase 6a: suppression matrix, one u64 word per thread ----
    {
#pragma clang fp contract(off)
        const int row = tid & 255, gq = tid >> 8;   // word gq of row
        float4 bi = sbox[row];
        float areai = fmaxf(bi.z - bi.x, 0.0f) * fmaxf(bi.w - bi.y, 0.0f);
        unsigned long long m = 0;
        const int jlo = gq * 64, jhi = jlo + 64;
        int start = row + 1 > jlo ? row + 1 : jlo;
        for (int jx = start; jx < jhi; ++jx) {
            float4 bj = sbox[jx];
            float areaj = fmaxf(bj.z - bj.x, 0.0f) * fmaxf(bj.w - bj.y, 0.0f);
            float lx = fmaxf(bi.x, bj.x), ly = fmaxf(bi.y, bj.y);
            float rx = fminf(bi.z, bj.z), ry = fminf(bi.w, bj.w);
            float iw = fmaxf(rx - lx, 0.0f), ih = fmaxf(ry - ly, 0.0f);
            float inter = iw * ih;
            float uni = areai + areaj - inter;
            float iou = inter / fmaxf(uni, 1e-8f);
            if (iou > IOU_T) m |= 1ull << (jx & 63);
        }
        supr[row][gq] = m;
    }
    // keep0 = score > 0 (threads 0..255 = waves 0..3)
    if (tid < K_N) {
        unsigned long long ball = __ballot(sscore[tid] > 0.0f);
        if ((tid & 63) == 0) keepw[tid >> 6] = ball;
    }
    __syncthreads();

    // ---- Phase 6b: serial greedy scan, 4 rows/group with hoisted loads.
    //      kc is read LIVE per row, so within-group suppression ordering
    //      matches the reference exactly. ----
    if (tid == 0) {
        unsigned long long k0 = keepw[0], k1 = keepw[1], k2 = keepw[2], k3 = keepw[3];
#define NMS_CHUNK(c, kc)                                                       \
        for (int l = 0; l < 64; l += 4) {                                      \
            const int i = (c) * 64 + l;                                        \
            unsigned long long wA0 = supr[i+0][0], wA1 = supr[i+0][1],         \
                               wA2 = supr[i+0][2], wA3 = supr[i+0][3];         \
            unsigned long long wB0 = supr[i+1][0], wB1 = supr[i+1][1],         \
                               wB2 = supr[i+1][2], wB3 = supr[i+1][3];         \
            unsigned long long wC0 = supr[i+2][0], wC1 = supr[i+2][1],         \
                               wC2 = supr[i+2][2], wC3 = supr[i+2][3];         \
            unsigned long long wD0 = supr[i+3][0], wD1 = supr[i+3][1],         \
                               wD2 = supr[i+3][2], wD3 = supr[i+3][3];         \
            if ((kc >> (l + 0)) & 1ull) { k0 &= ~wA0; k1 &= ~wA1; k2 &= ~wA2; k3 &= ~wA3; } \
            if ((kc >> (l + 1)) & 1ull) { k0 &= ~wB0; k1 &= ~wB1; k2 &= ~wB2; k3 &= ~wB3; } \
            if ((kc >> (l + 2)) & 1ull) { k0 &= ~wC0; k1 &= ~wC1; k2 &= ~wC2; k3 &= ~wC3; } \
            if ((kc >> (l + 3)) & 1ull) { k0 &= ~wD0; k1 &= ~wD1; k2 &= ~wD2; k3 &= ~wD3; } \
        }
        NMS_CHUNK(0, k0)
        NMS_CHUNK(1, k1)
        NMS_CHUNK(2, k2)
        NMS_CHUNK(3, k3)
#undef NMS_CHUNK
        keepw[0] = k0; keepw[1] = k1; keepw[2] = k2; keepw[3] = k3;
    }
    __syncthreads();

    // ---- Phase 7: outputs: dets [B,K,5] ++ labels [B,K] ++ keep [B,K] ----
    if (tid < K_N) {
        float keepf = ((keepw[tid >> 6] >> (tid & 63)) & 1ull) ? 1.0f : 0.0f;
        float4 bx = sbox[tid];
        float s = sscore[tid];
        float* det = out + ((size_t)b * K_N + tid) * 5;
        det[0] = bx.x * keepf;
        det[1] = bx.y * keepf;
        det[2] = bx.z * keepf;
        det[3] = bx.w * keepf;
        det[4] = s * keepf;
        out[(size_t)B_N * K_N * 5 + (size_t)b * K_N + tid] = (float)slab[tid];
        out[(size_t)B_N * K_N * 5 + (size_t)B_N * K_N + (size_t)b * K_N + tid] = keepf;
    }
}

extern "C" void kernel_launch(void* const* d_in, const int* in_sizes, int n_in,
                              void* d_out, int out_size, void* d_ws, size_t ws_size,
                              hipStream_t stream)
{
    const float* logits  = (const float*)d_in[0];   // [B,A,C] fp32
    const float* regs    = (const float*)d_in[1];   // [B,A,4] fp32
    const float* anchors = (const float*)d_in[2];   // [A,4]   fp32
    float* out = (float*)d_out;

    uint32_t* keys   = (uint32_t*)d_ws;                           // B*A u32
    uint8_t*  labels = (uint8_t*)(keys + (size_t)B_N * A_N);      // B*A u8

    const int total = B_N * A_N;                    // 392832 = 6138 * 64
    score_kernel<<<total / 64, 256, 0, stream>>>(logits, keys, labels);
    select_nms_kernel<<<B_N, 1024, 0, stream>>>(keys, labels, regs, anchors, out);
}